// Round 2
// baseline (104.355 us; speedup 1.0000x reference)
//
#include <hip/hip_runtime.h>
#include <math.h>

#define B_DIM    1024
#define IN_DIMS  512
#define OUT_DIMS 512
#define MOD_DIM  256
#define EPS_F    1e-8f

typedef __attribute__((ext_vector_type(8))) short bf16x8;
typedef __attribute__((ext_vector_type(4))) float f32x4;

__device__ __forceinline__ unsigned short f2bf(float f) {
    union { float f; unsigned u; } c; c.f = f;
    unsigned r = c.u + 0x7fffu + ((c.u >> 16) & 1u);   // RNE
    return (unsigned short)(r >> 16);
}
__device__ __forceinline__ float bf2f(unsigned short h) {
    union { float f; unsigned u; } c; c.u = ((unsigned)h) << 16;
    return c.f;
}

// async 16B/lane global->LDS (wave covers 64*16B = 1024B = one unpadded row)
__device__ __forceinline__ void gload_lds16(const void* g, void* l) {
    __builtin_amdgcn_global_load_lds(
        (const __attribute__((address_space(1))) unsigned int*)g,
        (__attribute__((address_space(3))) unsigned int*)l, 16, 0, 0);
}

// ---------------------------------------------------------------------------
// Fused kernel, REGULAR launch (graph-capture-safe) + software group barrier.
//   Phase 1 == verified k1 (colsum + split-bf16 mod-GEMM + demod -> t_bf)
//              + each block converts 2 weight rows (bx*64 + by*2 + {0,1})
//                to bf16 in ws -- exactly the rows its x-group consumes.
//   Barrier: ycnt[by]->8 (t rows ready), xcnt[bx]->32 (wbf rows ready).
//            Release: threadfence (buffer_wbl2) before arrive-add.
//            Acquire: threadfence (buffer_inv) after bounded spin.
//            Co-residency: LDS 103KB => 1 block/CU; grid 256 = #CUs.
//   Phase 2 == verified k2, B pre-converted bf16 (half bytes, no cvt VALU),
//              async global_load_lds staging, bias prefetched.
// grid (8,32) = 256 blocks, 256 thr = 4 waves (1 wave/SIMD).
// ---------------------------------------------------------------------------
#define LP1 264   // 528B rows  (33x16B) -> 2-way bank aliasing = free
#define LP2 536   // 1072B rows (67x16B) -> 2-way bank aliasing = free

__global__ __launch_bounds__(256) void fused(
    const float* __restrict__ mods,    // [1024,256]
    const float* __restrict__ mod_w,   // [512,256]
    const float* __restrict__ mod_b,   // [512]
    const float* __restrict__ weight,  // [512,512]
    const float* __restrict__ x,       // [1024,512]
    const float* __restrict__ bias,    // [512]
    unsigned short* __restrict__ t_bf, // ws: [1024,512] bf16
    unsigned short* __restrict__ wbf,  // ws: [512,512]  bf16
    int* __restrict__ cnts,            // ws: [32 ycnt][8 xcnt], memset 0
    float* __restrict__ out)           // [1024,512]
{
    __shared__ union SMem {
        struct {
            unsigned short Ah[32 * LP1];
            unsigned short Al[32 * LP1];
            unsigned short Bh[64 * LP1];
            unsigned short Bl[64 * LP1];
            float4 csm[16][16];
            float colsum[64];
        } p1;
        struct {
            unsigned short As[32 * LP2];
            unsigned short Bs[64 * LP2];
        } p2;
    } sm;

    const int tid = threadIdx.x;
    const int bx = blockIdx.x, by = blockIdx.y;
    const int n0 = bx * 64;
    const int m0 = by * 32;
    const int lane = tid & 63, wv = tid >> 6;
    const int wm = (wv >> 1) * 16, wn = (wv & 1) * 32;
    const int lr = lane & 15, lq = lane >> 4;

    // ================= PHASE 1 =================
    // ---- stage A (mods, 32x256): 8 float4/thread, split hi/lo ----
    #pragma unroll
    for (int i = 0; i < 8; i++) {
        const int id = tid + i * 256;
        const int r = id >> 6, c4 = id & 63;
        float4 v = *(const float4*)&mods[(m0 + r) * MOD_DIM + c4 * 4];
        ushort4 h, l;
        h.x = f2bf(v.x); l.x = f2bf(v.x - bf2f(h.x));
        h.y = f2bf(v.y); l.y = f2bf(v.y - bf2f(h.y));
        h.z = f2bf(v.z); l.z = f2bf(v.z - bf2f(h.z));
        h.w = f2bf(v.w); l.w = f2bf(v.w - bf2f(h.w));
        *(ushort4*)&sm.p1.Ah[r * LP1 + c4 * 4] = h;
        *(ushort4*)&sm.p1.Al[r * LP1 + c4 * 4] = l;
    }
    // ---- stage B (mod_w, 64x256): 16 float4/thread, split hi/lo ----
    #pragma unroll
    for (int i = 0; i < 16; i++) {
        const int id = tid + i * 256;
        const int r = id >> 6, c4 = id & 63;
        float4 v = *(const float4*)&mod_w[(n0 + r) * MOD_DIM + c4 * 4];
        ushort4 h, l;
        h.x = f2bf(v.x); l.x = f2bf(v.x - bf2f(h.x));
        h.y = f2bf(v.y); l.y = f2bf(v.y - bf2f(h.y));
        h.z = f2bf(v.z); l.z = f2bf(v.z - bf2f(h.z));
        h.w = f2bf(v.w); l.w = f2bf(v.w - bf2f(h.w));
        *(ushort4*)&sm.p1.Bh[r * LP1 + c4 * 4] = h;
        *(ushort4*)&sm.p1.Bl[r * LP1 + c4 * 4] = l;
    }

    // ---- weight fp32->bf16: rows bx*64 + by*2 + {0,1} (x-group-local) ----
    {
        const int row = n0 + by * 2 + (tid >> 7);
        const int c4 = tid & 127;
        float4 v = *(const float4*)&weight[row * IN_DIMS + c4 * 4];
        ushort4 h;
        h.x = f2bf(v.x); h.y = f2bf(v.y); h.z = f2bf(v.z); h.w = f2bf(v.w);
        *(ushort4*)&wbf[row * IN_DIMS + c4 * 4] = h;
    }

    // ---- prefetch epilogue x values (hide scattered-load latency) ----
    float xv[2][4];
    #pragma unroll
    for (int j = 0; j < 2; j++) {
        const int gn = n0 + wn + 16 * j + lr;
        #pragma unroll
        for (int rr = 0; rr < 4; rr++) {
            const int gm = m0 + wm + lq * 4 + rr;
            xv[j][rr] = x[gm * IN_DIMS + gn];
        }
    }

    // ---- colsum for this block's 64 cols: 32 coalesced float4 rounds ----
    {
        const int c4 = tid & 15, rr = tid >> 4;
        float4 acc = {0.f, 0.f, 0.f, 0.f};
        #pragma unroll
        for (int it = 0; it < 32; it++) {
            const int row = rr + 16 * it;
            float4 v = *(const float4*)&weight[row * IN_DIMS + n0 + c4 * 4];
            acc.x += v.x * v.x; acc.y += v.y * v.y;
            acc.z += v.z * v.z; acc.w += v.w * v.w;
        }
        sm.p1.csm[rr][c4] = acc;
    }
    __syncthreads();
    if (tid < 16) {
        float4 s = sm.p1.csm[0][tid];
        #pragma unroll
        for (int j = 1; j < 16; j++) {
            float4 v = sm.p1.csm[j][tid];
            s.x += v.x; s.y += v.y; s.z += v.z; s.w += v.w;
        }
        *(float4*)&sm.p1.colsum[tid * 4] = s;
    }

    // ---- MFMA: 8 kk-steps, 6 MFMA each (hh, hl, lh) ----
    f32x4 acc[2] = {};
    #pragma unroll
    for (int kk = 0; kk < 256; kk += 32) {
        const int ko = kk + lq * 8;
        bf16x8 ah = *(bf16x8*)&sm.p1.Ah[(wm + lr) * LP1 + ko];
        bf16x8 al = *(bf16x8*)&sm.p1.Al[(wm + lr) * LP1 + ko];
        bf16x8 bh0 = *(bf16x8*)&sm.p1.Bh[(wn +      lr) * LP1 + ko];
        bf16x8 bh1 = *(bf16x8*)&sm.p1.Bh[(wn + 16 + lr) * LP1 + ko];
        bf16x8 bl0 = *(bf16x8*)&sm.p1.Bl[(wn +      lr) * LP1 + ko];
        bf16x8 bl1 = *(bf16x8*)&sm.p1.Bl[(wn + 16 + lr) * LP1 + ko];
        acc[0] = __builtin_amdgcn_mfma_f32_16x16x32_bf16(ah, bh0, acc[0], 0, 0, 0);
        acc[1] = __builtin_amdgcn_mfma_f32_16x16x32_bf16(ah, bh1, acc[1], 0, 0, 0);
        acc[0] = __builtin_amdgcn_mfma_f32_16x16x32_bf16(ah, bl0, acc[0], 0, 0, 0);
        acc[1] = __builtin_amdgcn_mfma_f32_16x16x32_bf16(ah, bl1, acc[1], 0, 0, 0);
        acc[0] = __builtin_amdgcn_mfma_f32_16x16x32_bf16(al, bh0, acc[0], 0, 0, 0);
        acc[1] = __builtin_amdgcn_mfma_f32_16x16x32_bf16(al, bh1, acc[1], 0, 0, 0);
    }
    __syncthreads();   // colsum visibility for all waves

    // ---- epilogue: s -> t = x*s*rsqrt(s^2*colsum+eps) -> bf16 (to ws) ----
    // C/D layout: col = lane&15, row = (lane>>4)*4 + reg
    #pragma unroll
    for (int j = 0; j < 2; j++) {
        const int ln = wn + 16 * j + lr;
        const int gn = n0 + ln;
        const float cs = sm.p1.colsum[ln];
        const float mb = mod_b[gn];
        #pragma unroll
        for (int rr = 0; rr < 4; rr++) {
            const int gm = m0 + wm + lq * 4 + rr;
            const float s = acc[j][rr] + mb;
            const float tv = xv[j][rr] * s * rsqrtf(s * s * cs + EPS_F);
            t_bf[gm * IN_DIMS + gn] = f2bf(tv);
        }
    }

    // ================= SOFTWARE GROUP BARRIER =================
    __syncthreads();               // all waves drained (vmcnt(0) before barrier)
    if (tid == 0) {
        __threadfence();           // release: buffer_wbl2 sc1 -> IF$
        __hip_atomic_fetch_add(&cnts[by], 1,
                               __ATOMIC_RELEASE, __HIP_MEMORY_SCOPE_AGENT);
        __hip_atomic_fetch_add(&cnts[32 + bx], 1,
                               __ATOMIC_RELEASE, __HIP_MEMORY_SCOPE_AGENT);
        int guard = 0;
        while (guard < 300000) {   // bounded: fail->wrong answer, not hang
            int yv = __hip_atomic_load(&cnts[by],
                                       __ATOMIC_RELAXED, __HIP_MEMORY_SCOPE_AGENT);
            int xvv = __hip_atomic_load(&cnts[32 + bx],
                                        __ATOMIC_RELAXED, __HIP_MEMORY_SCOPE_AGENT);
            if (yv >= 8 && xvv >= 32) break;
            __builtin_amdgcn_s_sleep(2);
            guard++;
        }
    }
    __syncthreads();
    __threadfence();               // acquire: buffer_inv sc1 (fresh reads)

    // ================= PHASE 2 =================
    const float bv0 = bias[n0 + wn + lr];
    const float bv1 = bias[n0 + wn + 16 + lr];

    // ---- stage A (t_bf, 32x512 bf16): async, 8 rows/wave, 1 issue/row ----
    #pragma unroll
    for (int i = 0; i < 8; i++) {
        const int r = wv * 8 + i;
        gload_lds16(t_bf + (m0 + r) * IN_DIMS + lane * 8, &sm.p2.As[r * LP2]);
    }
    // ---- stage B (wbf, 64x512 bf16): async, 16 rows/wave ----
    #pragma unroll
    for (int i = 0; i < 16; i++) {
        const int r = wv * 16 + i;
        gload_lds16(wbf + (n0 + r) * IN_DIMS + lane * 8, &sm.p2.Bs[r * LP2]);
    }
    __syncthreads();   // drains vmcnt (incl. global_load_lds)

    f32x4 acc2[2] = {};
    #pragma unroll
    for (int kk = 0; kk < 512; kk += 32) {
        const int ko = kk + lq * 8;
        bf16x8 a  = *(bf16x8*)&sm.p2.As[(wm + lr) * LP2 + ko];
        bf16x8 b0 = *(bf16x8*)&sm.p2.Bs[(wn +      lr) * LP2 + ko];
        bf16x8 b1 = *(bf16x8*)&sm.p2.Bs[(wn + 16 + lr) * LP2 + ko];
        acc2[0] = __builtin_amdgcn_mfma_f32_16x16x32_bf16(a, b0, acc2[0], 0, 0, 0);
        acc2[1] = __builtin_amdgcn_mfma_f32_16x16x32_bf16(a, b1, acc2[1], 0, 0, 0);
    }

    #pragma unroll
    for (int j = 0; j < 2; j++) {
        const int gn = n0 + wn + 16 * j + lr;
        const float bvv = j ? bv1 : bv0;
        #pragma unroll
        for (int rr = 0; rr < 4; rr++) {
            const int gm = m0 + wm + lq * 4 + rr;
            out[gm * OUT_DIMS + gn] = acc2[j][rr] + bvv;
        }
    }
}

extern "C" void kernel_launch(void* const* d_in, const int* in_sizes, int n_in,
                              void* d_out, int out_size, void* d_ws, size_t ws_size,
                              hipStream_t stream)
{
    const float* modulations = (const float*)d_in[0]; // [1024, 256]
    const float* x           = (const float*)d_in[1]; // [1024, 512]
    const float* weight      = (const float*)d_in[2]; // [512, 512]
    const float* bias        = (const float*)d_in[3]; // [512]
    const float* mod_w       = (const float*)d_in[4]; // [512, 256]
    const float* mod_b       = (const float*)d_in[5]; // [512]
    float* out = (float*)d_out;                       // [1024, 512]

    unsigned short* t_bf = (unsigned short*)d_ws;                  // 1 MB
    unsigned short* wbf  = (unsigned short*)d_ws + (1024 * 512);   // 512 KB
    int* cnts = (int*)((char*)d_ws + (4 << 20));                   // 256 B

    // zero the barrier counters (graph-capturable memset node)
    hipMemsetAsync(cnts, 0, 256, stream);

    fused<<<dim3(8, 32), 256, 0, stream>>>(
        modulations, mod_w, mod_b, weight, x, bias, t_bf, wbf, cnts, out);
}

// Round 3
// 75.209 us; speedup vs baseline: 1.3875x; 1.3875x over previous
//
#include <hip/hip_runtime.h>
#include <math.h>

#define B_DIM    1024
#define IN_DIMS  512
#define OUT_DIMS 512
#define MOD_DIM  256
#define EPS_F    1e-8f

typedef __attribute__((ext_vector_type(8))) short bf16x8;
typedef __attribute__((ext_vector_type(4))) float f32x4;

__device__ __forceinline__ unsigned short f2bf(float f) {
    union { float f; unsigned u; } c; c.f = f;
    unsigned r = c.u + 0x7fffu + ((c.u >> 16) & 1u);   // RNE
    return (unsigned short)(r >> 16);
}
__device__ __forceinline__ float bf2f(unsigned short h) {
    union { float f; unsigned u; } c; c.u = ((unsigned)h) << 16;
    return c.f;
}

// async 16B/lane global->LDS (wave covers 64*16B = 1024B = one unpadded row)
__device__ __forceinline__ void gload_lds16(const void* g, void* l) {
    __builtin_amdgcn_global_load_lds(
        (const __attribute__((address_space(1))) unsigned int*)g,
        (__attribute__((address_space(3))) unsigned int*)l, 16, 0, 0);
}

// ---------------------------------------------------------------------------
// K1: colsum + split-bf16 mod-GEMM + demod epilogue -> t_bf, PLUS one-time
// weight fp32->bf16 conversion (2 rows/block) -> wbf for K2.
// 512 threads = 8 waves (2 waves/SIMD -- 2x the latency hiding of the 77µs
// baseline; per-thread staging work halves). Same 32x64 tile, K=256 one-shot,
// same split numerics (hh+hl+lh), ONE main barrier.
// LDS ~110 KB -> 1 block/CU; grid (8,32) = 256 blocks = 1/CU.
// ---------------------------------------------------------------------------
#define LP1 264   // 528B rows (33x16B) -> 2-way bank aliasing = free
__global__ __launch_bounds__(512) void k1_mod(
    const float* __restrict__ mods,    // [1024,256]
    const float* __restrict__ mod_w,   // [512,256]
    const float* __restrict__ mod_b,   // [512]
    const float* __restrict__ weight,  // [512,512]
    const float* __restrict__ x,       // [1024,512]
    unsigned short* __restrict__ t_bf, // [1024,512] bf16
    unsigned short* __restrict__ wbf)  // [512,512]  bf16
{
    __shared__ unsigned short Ah[32 * LP1], Al[32 * LP1];
    __shared__ unsigned short Bh[64 * LP1], Bl[64 * LP1];
    __shared__ float4 csm[32][16];
    __shared__ float colsum_s[64];

    const int tid = threadIdx.x;
    const int n0 = blockIdx.x * 64;
    const int m0 = blockIdx.y * 32;
    const int lane = tid & 63, wv = tid >> 6;          // 8 waves
    const int wm = (wv >> 2) * 16, wn = (wv & 3) * 16; // 2x4 wave grid -> 16x16/wave
    const int lr = lane & 15, lq = lane >> 4;

    // ---- stage A (mods, 32x256): 4 float4/thread, split hi/lo ----
    #pragma unroll
    for (int i = 0; i < 4; i++) {
        const int id = tid + i * 512;
        const int r = id >> 6, c4 = id & 63;
        float4 v = *(const float4*)&mods[(m0 + r) * MOD_DIM + c4 * 4];
        ushort4 h, l;
        h.x = f2bf(v.x); l.x = f2bf(v.x - bf2f(h.x));
        h.y = f2bf(v.y); l.y = f2bf(v.y - bf2f(h.y));
        h.z = f2bf(v.z); l.z = f2bf(v.z - bf2f(h.z));
        h.w = f2bf(v.w); l.w = f2bf(v.w - bf2f(h.w));
        *(ushort4*)&Ah[r * LP1 + c4 * 4] = h;
        *(ushort4*)&Al[r * LP1 + c4 * 4] = l;
    }
    // ---- stage B (mod_w, 64x256): 8 float4/thread, split hi/lo ----
    #pragma unroll
    for (int i = 0; i < 8; i++) {
        const int id = tid + i * 512;
        const int r = id >> 6, c4 = id & 63;
        float4 v = *(const float4*)&mod_w[(n0 + r) * MOD_DIM + c4 * 4];
        ushort4 h, l;
        h.x = f2bf(v.x); l.x = f2bf(v.x - bf2f(h.x));
        h.y = f2bf(v.y); l.y = f2bf(v.y - bf2f(h.y));
        h.z = f2bf(v.z); l.z = f2bf(v.z - bf2f(h.z));
        h.w = f2bf(v.w); l.w = f2bf(v.w - bf2f(h.w));
        *(ushort4*)&Bh[r * LP1 + c4 * 4] = h;
        *(ushort4*)&Bl[r * LP1 + c4 * 4] = l;
    }

    // ---- weight fp32->bf16 prep for K2: rows bx*64 + by*2 + {0,1} ----
    // (each x-group converts exactly the 64 rows its K2 blocks consume;
    //  each row written once across the grid)
    if (tid < 256) {
        const int row = n0 + blockIdx.y * 2 + (tid >> 7);
        const int c4 = tid & 127;
        float4 v = *(const float4*)&weight[row * IN_DIMS + c4 * 4];
        ushort4 h;
        h.x = f2bf(v.x); h.y = f2bf(v.y); h.z = f2bf(v.z); h.w = f2bf(v.w);
        *(ushort4*)&wbf[row * IN_DIMS + c4 * 4] = h;
    }

    // ---- prefetch epilogue x values (hide scattered-load latency) ----
    float xv[4];
    {
        const int gn = n0 + wn + lr;
        #pragma unroll
        for (int rr = 0; rr < 4; rr++) {
            const int gm = m0 + wm + lq * 4 + rr;
            xv[rr] = x[gm * IN_DIMS + gn];
        }
    }

    // ---- colsum for this block's 64 cols: 16 coalesced float4 rounds ----
    {
        const int c4 = tid & 15, rr = tid >> 4;        // 32 row-groups
        float4 acc = {0.f, 0.f, 0.f, 0.f};
        #pragma unroll
        for (int it = 0; it < 16; it++) {
            const int row = rr + 32 * it;
            float4 v = *(const float4*)&weight[row * IN_DIMS + n0 + c4 * 4];
            acc.x += v.x * v.x; acc.y += v.y * v.y;
            acc.z += v.z * v.z; acc.w += v.w * v.w;
        }
        csm[rr][c4] = acc;
    }
    __syncthreads();
    if (tid < 16) {
        float4 s = csm[0][tid];
        #pragma unroll
        for (int j = 1; j < 32; j++) {
            float4 v = csm[j][tid];
            s.x += v.x; s.y += v.y; s.z += v.z; s.w += v.w;
        }
        *(float4*)&colsum_s[tid * 4] = s;
    }

    // ---- MFMA: 8 kk-steps, 3 MFMA each (hh, hl, lh), 16x16 out/wave ----
    f32x4 acc = {};
    #pragma unroll
    for (int kk = 0; kk < 256; kk += 32) {
        const int ko = kk + lq * 8;
        bf16x8 ah = *(bf16x8*)&Ah[(wm + lr) * LP1 + ko];
        bf16x8 al = *(bf16x8*)&Al[(wm + lr) * LP1 + ko];
        bf16x8 bh = *(bf16x8*)&Bh[(wn + lr) * LP1 + ko];
        bf16x8 bl = *(bf16x8*)&Bl[(wn + lr) * LP1 + ko];
        acc = __builtin_amdgcn_mfma_f32_16x16x32_bf16(ah, bh, acc, 0, 0, 0);
        acc = __builtin_amdgcn_mfma_f32_16x16x32_bf16(ah, bl, acc, 0, 0, 0);
        acc = __builtin_amdgcn_mfma_f32_16x16x32_bf16(al, bh, acc, 0, 0, 0);
    }
    __syncthreads();   // colsum_s visibility for all waves

    // ---- epilogue: s -> t = x*s*rsqrt(s^2*colsum+eps) -> bf16 ----
    // C/D layout: col = lane&15, row = (lane>>4)*4 + reg
    {
        const int ln = wn + lr;
        const int gn = n0 + ln;
        const float cs = colsum_s[ln];
        const float mb = mod_b[gn];
        #pragma unroll
        for (int rr = 0; rr < 4; rr++) {
            const int gm = m0 + wm + lq * 4 + rr;
            const float s = acc[rr] + mb;
            const float tv = xv[rr] * s * rsqrtf(s * s * cs + EPS_F);
            t_bf[gm * IN_DIMS + gn] = f2bf(tv);
        }
    }
}

// ---------------------------------------------------------------------------
// K2: out = t_bf @ wbf^T + bias. Both operands pre-converted bf16 -> async
// global_load_lds staging only (no fp32 loads, no convert VALU: B bytes and
// B load count HALVED vs the 77µs baseline). 512 thr = 8 waves (2/SIMD).
// Tile 32x64, K=512 one-shot, ONE barrier. LDS ~101 KB -> 1 block/CU.
// ---------------------------------------------------------------------------
#define LP2 536   // 1072B rows (67x16B) -> 2-way bank aliasing = free
__global__ __launch_bounds__(512) void k2_out(
    const unsigned short* __restrict__ t_bf, // [1024,512] bf16
    const unsigned short* __restrict__ wbf,  // [512,512]  bf16
    const float* __restrict__ bias,          // [512]
    float* __restrict__ out)                 // [1024,512]
{
    __shared__ unsigned short As[32 * LP2];
    __shared__ unsigned short Bs[64 * LP2];

    const int tid = threadIdx.x;
    const int n0 = blockIdx.x * 64;
    const int m0 = blockIdx.y * 32;
    const int lane = tid & 63, wv = tid >> 6;          // 8 waves
    const int wm = (wv >> 2) * 16, wn = (wv & 3) * 16;
    const int lr = lane & 15, lq = lane >> 4;

    // bias prefetch (hide latency under staging)
    const float bv = bias[n0 + wn + lr];

    // ---- stage A (t_bf, 32x512 bf16): async, 4 rows/wave, 1 issue/row ----
    #pragma unroll
    for (int i = 0; i < 4; i++) {
        const int r = wv * 4 + i;
        gload_lds16(t_bf + (m0 + r) * IN_DIMS + lane * 8, &As[r * LP2]);
    }
    // ---- stage B (wbf, 64x512 bf16): async, 8 rows/wave ----
    #pragma unroll
    for (int i = 0; i < 8; i++) {
        const int r = wv * 8 + i;
        gload_lds16(wbf + (n0 + r) * IN_DIMS + lane * 8, &Bs[r * LP2]);
    }
    __syncthreads();   // drains vmcnt (incl. global_load_lds)

    f32x4 acc = {};
    #pragma unroll
    for (int kk = 0; kk < 512; kk += 32) {
        const int ko = kk + lq * 8;
        bf16x8 a = *(bf16x8*)&As[(wm + lr) * LP2 + ko];
        bf16x8 b = *(bf16x8*)&Bs[(wn + lr) * LP2 + ko];
        acc = __builtin_amdgcn_mfma_f32_16x16x32_bf16(a, b, acc, 0, 0, 0);
    }

    {
        const int gn = n0 + wn + lr;
        #pragma unroll
        for (int rr = 0; rr < 4; rr++) {
            const int gm = m0 + wm + lq * 4 + rr;
            out[gm * OUT_DIMS + gn] = acc[rr] + bv;
        }
    }
}

extern "C" void kernel_launch(void* const* d_in, const int* in_sizes, int n_in,
                              void* d_out, int out_size, void* d_ws, size_t ws_size,
                              hipStream_t stream)
{
    const float* modulations = (const float*)d_in[0]; // [1024, 256]
    const float* x           = (const float*)d_in[1]; // [1024, 512]
    const float* weight      = (const float*)d_in[2]; // [512, 512]
    const float* bias        = (const float*)d_in[3]; // [512]
    const float* mod_w       = (const float*)d_in[4]; // [512, 256]
    const float* mod_b       = (const float*)d_in[5]; // [512]
    float* out = (float*)d_out;                       // [1024, 512]

    unsigned short* t_bf = (unsigned short*)d_ws;                  // 1 MB
    unsigned short* wbf  = (unsigned short*)d_ws + (1024 * 512);   // 512 KB

    k1_mod<<<dim3(8, 32), 512, 0, stream>>>(
        modulations, mod_w, mod_b, weight, x, t_bf, wbf);

    k2_out<<<dim3(8, 32), 512, 0, stream>>>(
        t_bf, wbf, bias, out);
}

// Round 4
// 74.659 us; speedup vs baseline: 1.3978x; 1.0074x over previous
//
#include <hip/hip_runtime.h>
#include <math.h>

#define B_DIM    1024
#define IN_DIMS  512
#define OUT_DIMS 512
#define MOD_DIM  256
#define EPS_F    1e-8f

typedef __attribute__((ext_vector_type(8))) short bf16x8;
typedef __attribute__((ext_vector_type(4))) float f32x4;

__device__ __forceinline__ unsigned short f2bf(float f) {
    union { float f; unsigned u; } c; c.f = f;
    unsigned r = c.u + 0x7fffu + ((c.u >> 16) & 1u);   // RNE
    return (unsigned short)(r >> 16);
}
__device__ __forceinline__ float bf2f(unsigned short h) {
    union { float f; unsigned u; } c; c.u = ((unsigned)h) << 16;
    return c.f;
}

// async 16B/lane global->LDS (wave covers 64*16B = 1024B = one unpadded row)
__device__ __forceinline__ void gload_lds16(const void* g, void* l) {
    __builtin_amdgcn_global_load_lds(
        (const __attribute__((address_space(1))) unsigned int*)g,
        (__attribute__((address_space(3))) unsigned int*)l, 16, 0, 0);
}

// ---------------------------------------------------------------------------
// Round 4: 2 blocks/CU for straggler-packing + cross-block latency overlap.
// Tiles halved to 32x32, blocks 256 thr (4 waves), grid (16,32)=512 blocks.
// k1 LDS ~70 KB, k2 LDS ~67 KB -> 2 blocks/CU; __launch_bounds__(256,2)
// caps VGPR at 256 so registers don't block 2-deep occupancy.
// Numerics bit-identical to the verified kernel: same f2bf RNE, same
// hh+hl+lh split MFMA, same colsum summation tree (row = rr + 32*it,
// rr in [0,32), then linear 0..31 reduce), same K-order in both GEMMs.
// ---------------------------------------------------------------------------
#define LP1 264   // 528B rows (33x16B): rows step 4 banks -> 2-way = free
#define LP2 536   // 1072B rows (67x16B): rows step 12 banks -> 2-way = free

__global__ __launch_bounds__(256, 2) void k1_mod(
    const float* __restrict__ mods,    // [1024,256]
    const float* __restrict__ mod_w,   // [512,256]
    const float* __restrict__ mod_b,   // [512]
    const float* __restrict__ weight,  // [512,512]
    const float* __restrict__ x,       // [1024,512]
    unsigned short* __restrict__ t_bf, // [1024,512] bf16
    unsigned short* __restrict__ wbf)  // [512,512]  bf16
{
    __shared__ unsigned short Ah[32 * LP1], Al[32 * LP1];   // 33.8 KB
    __shared__ unsigned short Bh[32 * LP1], Bl[32 * LP1];   // 33.8 KB
    __shared__ float4 csm[32][8];                           // 4 KB
    __shared__ float colsum_s[32];

    const int tid = threadIdx.x;
    const int n0 = blockIdx.x * 32;     // 16 n-tiles
    const int m0 = blockIdx.y * 32;     // 32 m-tiles
    const int lane = tid & 63, wv = tid >> 6;              // 4 waves
    const int wm = (wv >> 1) * 16, wn = (wv & 1) * 16;     // 2x2 wave grid
    const int lr = lane & 15, lq = lane >> 4;

    // ---- stage A (mods, 32x256): 8 float4/thread, split hi/lo ----
    #pragma unroll
    for (int i = 0; i < 8; i++) {
        const int id = tid + i * 256;
        const int r = id >> 6, c4 = id & 63;
        float4 v = *(const float4*)&mods[(m0 + r) * MOD_DIM + c4 * 4];
        ushort4 h, l;
        h.x = f2bf(v.x); l.x = f2bf(v.x - bf2f(h.x));
        h.y = f2bf(v.y); l.y = f2bf(v.y - bf2f(h.y));
        h.z = f2bf(v.z); l.z = f2bf(v.z - bf2f(h.z));
        h.w = f2bf(v.w); l.w = f2bf(v.w - bf2f(h.w));
        *(ushort4*)&Ah[r * LP1 + c4 * 4] = h;
        *(ushort4*)&Al[r * LP1 + c4 * 4] = l;
    }
    // ---- stage B (mod_w, 32x256): 8 float4/thread, split hi/lo ----
    #pragma unroll
    for (int i = 0; i < 8; i++) {
        const int id = tid + i * 256;
        const int r = id >> 6, c4 = id & 63;
        float4 v = *(const float4*)&mod_w[(n0 + r) * MOD_DIM + c4 * 4];
        ushort4 h, l;
        h.x = f2bf(v.x); l.x = f2bf(v.x - bf2f(h.x));
        h.y = f2bf(v.y); l.y = f2bf(v.y - bf2f(h.y));
        h.z = f2bf(v.z); l.z = f2bf(v.z - bf2f(h.z));
        h.w = f2bf(v.w); l.w = f2bf(v.w - bf2f(h.w));
        *(ushort4*)&Bh[r * LP1 + c4 * 4] = h;
        *(ushort4*)&Bl[r * LP1 + c4 * 4] = l;
    }

    // ---- weight fp32->bf16 prep for K2: 1 row/block (row = by*16+bx) ----
    // bijection over [0,512): every wbf row written exactly once.
    if (tid < 128) {
        const int row = blockIdx.y * 16 + blockIdx.x;
        float4 v = *(const float4*)&weight[row * IN_DIMS + tid * 4];
        ushort4 h;
        h.x = f2bf(v.x); h.y = f2bf(v.y); h.z = f2bf(v.z); h.w = f2bf(v.w);
        *(ushort4*)&wbf[row * IN_DIMS + tid * 4] = h;
    }

    // ---- prefetch epilogue x values (hide scattered-load latency) ----
    float xv[4];
    {
        const int gn = n0 + wn + lr;
        #pragma unroll
        for (int rr = 0; rr < 4; rr++) {
            const int gm = m0 + wm + lq * 4 + rr;
            xv[rr] = x[gm * IN_DIMS + gn];
        }
    }

    // ---- colsum for this block's 32 cols: 16 coalesced float4 rounds ----
    // same summation tree as verified kernel: row = rr + 32*it, rr in [0,32)
    {
        const int c4 = tid & 7, rr = tid >> 3;             // 32 row-groups x 8 f4-cols
        float4 acc = {0.f, 0.f, 0.f, 0.f};
        #pragma unroll
        for (int it = 0; it < 16; it++) {
            const int row = rr + 32 * it;
            float4 v = *(const float4*)&weight[row * IN_DIMS + n0 + c4 * 4];
            acc.x += v.x * v.x; acc.y += v.y * v.y;
            acc.z += v.z * v.z; acc.w += v.w * v.w;
        }
        csm[rr][c4] = acc;
    }
    __syncthreads();
    if (tid < 8) {
        float4 s = csm[0][tid];
        #pragma unroll
        for (int j = 1; j < 32; j++) {
            float4 v = csm[j][tid];
            s.x += v.x; s.y += v.y; s.z += v.z; s.w += v.w;
        }
        *(float4*)&colsum_s[tid * 4] = s;
    }

    // ---- MFMA: 8 kk-steps, 3 MFMA each (hh, hl, lh), 16x16 out/wave ----
    f32x4 acc = {};
    #pragma unroll
    for (int kk = 0; kk < 256; kk += 32) {
        const int ko = kk + lq * 8;
        bf16x8 ah = *(bf16x8*)&Ah[(wm + lr) * LP1 + ko];
        bf16x8 al = *(bf16x8*)&Al[(wm + lr) * LP1 + ko];
        bf16x8 bh = *(bf16x8*)&Bh[(wn + lr) * LP1 + ko];
        bf16x8 bl = *(bf16x8*)&Bl[(wn + lr) * LP1 + ko];
        acc = __builtin_amdgcn_mfma_f32_16x16x32_bf16(ah, bh, acc, 0, 0, 0);
        acc = __builtin_amdgcn_mfma_f32_16x16x32_bf16(ah, bl, acc, 0, 0, 0);
        acc = __builtin_amdgcn_mfma_f32_16x16x32_bf16(al, bh, acc, 0, 0, 0);
    }
    __syncthreads();   // colsum_s visibility for all waves

    // ---- epilogue: s -> t = x*s*rsqrt(s^2*colsum+eps) -> bf16 ----
    // C/D layout: col = lane&15, row = (lane>>4)*4 + reg
    {
        const int ln = wn + lr;
        const int gn = n0 + ln;
        const float cs = colsum_s[ln];
        const float mb = mod_b[gn];
        #pragma unroll
        for (int rr = 0; rr < 4; rr++) {
            const int gm = m0 + wm + lq * 4 + rr;
            const float s = acc[rr] + mb;
            const float tv = xv[rr] * s * rsqrtf(s * s * cs + EPS_F);
            t_bf[gm * IN_DIMS + gn] = f2bf(tv);
        }
    }
}

// ---------------------------------------------------------------------------
// K2: out = t_bf @ wbf^T + bias, both operands pre-converted bf16 (async
// global_load_lds staging only). 32x32 tile, 256 thr, 2 blocks/CU.
// ---------------------------------------------------------------------------
__global__ __launch_bounds__(256, 2) void k2_out(
    const unsigned short* __restrict__ t_bf, // [1024,512] bf16
    const unsigned short* __restrict__ wbf,  // [512,512]  bf16
    const float* __restrict__ bias,          // [512]
    float* __restrict__ out)                 // [1024,512]
{
    __shared__ unsigned short As[32 * LP2];   // 33.5 KB
    __shared__ unsigned short Bs[32 * LP2];   // 33.5 KB

    const int tid = threadIdx.x;
    const int n0 = blockIdx.x * 32;
    const int m0 = blockIdx.y * 32;
    const int lane = tid & 63, wv = tid >> 6;              // 4 waves
    const int wm = (wv >> 1) * 16, wn = (wv & 1) * 16;     // 2x2 wave grid
    const int lr = lane & 15, lq = lane >> 4;

    // bias prefetch (hide latency under staging)
    const float bv = bias[n0 + wn + lr];

    // ---- stage A (t_bf, 32x512 bf16): async, 8 rows/wave, 1 issue/row ----
    #pragma unroll
    for (int i = 0; i < 8; i++) {
        const int r = wv * 8 + i;
        gload_lds16(t_bf + (m0 + r) * IN_DIMS + lane * 8, &As[r * LP2]);
    }
    // ---- stage B (wbf, 32x512 bf16): async, 8 rows/wave ----
    #pragma unroll
    for (int i = 0; i < 8; i++) {
        const int r = wv * 8 + i;
        gload_lds16(wbf + (n0 + r) * IN_DIMS + lane * 8, &Bs[r * LP2]);
    }
    __syncthreads();   // drains vmcnt (incl. global_load_lds)

    f32x4 acc = {};
    #pragma unroll
    for (int kk = 0; kk < 512; kk += 32) {
        const int ko = kk + lq * 8;
        bf16x8 a = *(bf16x8*)&As[(wm + lr) * LP2 + ko];
        bf16x8 b = *(bf16x8*)&Bs[(wn + lr) * LP2 + ko];
        acc = __builtin_amdgcn_mfma_f32_16x16x32_bf16(a, b, acc, 0, 0, 0);
    }

    {
        const int gn = n0 + wn + lr;
        #pragma unroll
        for (int rr = 0; rr < 4; rr++) {
            const int gm = m0 + wm + lq * 4 + rr;
            out[gm * OUT_DIMS + gn] = acc[rr] + bv;
        }
    }
}

extern "C" void kernel_launch(void* const* d_in, const int* in_sizes, int n_in,
                              void* d_out, int out_size, void* d_ws, size_t ws_size,
                              hipStream_t stream)
{
    const float* modulations = (const float*)d_in[0]; // [1024, 256]
    const float* x           = (const float*)d_in[1]; // [1024, 512]
    const float* weight      = (const float*)d_in[2]; // [512, 512]
    const float* bias        = (const float*)d_in[3]; // [512]
    const float* mod_w       = (const float*)d_in[4]; // [512, 256]
    const float* mod_b       = (const float*)d_in[5]; // [512]
    float* out = (float*)d_out;                       // [1024, 512]

    unsigned short* t_bf = (unsigned short*)d_ws;                  // 1 MB
    unsigned short* wbf  = (unsigned short*)d_ws + (1024 * 512);   // 512 KB

    k1_mod<<<dim3(16, 32), 256, 0, stream>>>(
        modulations, mod_w, mod_b, weight, x, t_bf, wbf);

    k2_out<<<dim3(16, 32), 256, 0, stream>>>(
        t_bf, wbf, bias, out);
}